// Round 4
// baseline (286.881 us; speedup 1.0000x reference)
//
#include <hip/hip_runtime.h>

#define NN 2048      // nodes per batch
#define FF 128       // features per node
#define KK 16        // top-K
#define INF_KEY 0xFFFFFFFFFFFFFFFFull

typedef float f32x4 __attribute__((ext_vector_type(4)));

// ---------- wave64 min-reduce via DPP (VALU pipe, no LDS/permute) ----------
__device__ __forceinline__ unsigned wave_min_u32(unsigned x) {
    int v = (int)x, t;
    t = __builtin_amdgcn_update_dpp(v, v, 0x111, 0xf, 0xf, false); // row_shr:1
    v = ((unsigned)t < (unsigned)v) ? t : v;
    t = __builtin_amdgcn_update_dpp(v, v, 0x112, 0xf, 0xf, false); // row_shr:2
    v = ((unsigned)t < (unsigned)v) ? t : v;
    t = __builtin_amdgcn_update_dpp(v, v, 0x114, 0xf, 0xf, false); // row_shr:4
    v = ((unsigned)t < (unsigned)v) ? t : v;
    t = __builtin_amdgcn_update_dpp(v, v, 0x118, 0xf, 0xf, false); // row_shr:8
    v = ((unsigned)t < (unsigned)v) ? t : v;
    t = __builtin_amdgcn_update_dpp(v, v, 0x142, 0xf, 0xf, false); // row_bcast:15
    v = ((unsigned)t < (unsigned)v) ? t : v;
    t = __builtin_amdgcn_update_dpp(v, v, 0x143, 0xf, 0xf, false); // row_bcast:31
    v = ((unsigned)t < (unsigned)v) ? t : v;
    return (unsigned)__builtin_amdgcn_readlane(v, 63);
}

// Pack xyz (first 3 of 128 features) into a compact f32x4 array in the
// workspace: 512 KB total, fully L2-resident, read by every fused block.
__global__ __launch_bounds__(256) void pack_xyz(
    const float* __restrict__ nodes, f32x4* __restrict__ out, int total)
{
    const int t = blockIdx.x * 256 + threadIdx.x;
    if (t < total) {
        const float* p = nodes + (size_t)t * FF;
        out[t] = (f32x4){p[0], p[1], p[2], 0.f};
    }
}

// xyz fetch: PACKED -> one coalesced 16B load from the packed L2-resident
// array; fallback -> 3 scalar loads from nodes (identical float bits either
// way, so the (d2,index) key stream is unchanged -> absmax 0).
template<bool PACKED>
__device__ __forceinline__ f32x4 load_xyz(const float* __restrict__ base, int idx) {
    if constexpr (PACKED) {
        return ((const f32x4*)base)[idx];
    } else {
        const float* p = base + (size_t)idx * FF;
        return (f32x4){p[0], p[1], p[2], 0.f};
    }
}

// Fused, NO LDS STAGING, NO BARRIER (R4 ablation of the staging phase):
// one block = 4 rows (4 waves, 256 thr). Build loop reads packed[j] straight
// from L2 (1 KB/wave/instr coalesced). Verified one-pass per-lane sorted
// top-4 queue + 16 DPP extraction rounds + 1KB LDS word table -> coalesced
// nontemporal f32x4 row stores. Strict-IEEE non-contracted d2; key order ==
// jax top_k (d2,index) lexicographic.
template<bool PACKED>
__global__ __launch_bounds__(256, 8) void knn_adj_fused(
    const float* __restrict__ xyz,     // PACKED ? packed f32x4 base : nodes
    const int*   __restrict__ T_arr,
    const int*   __restrict__ tau_arr,
    float*       __restrict__ adj)
{
    const int b    = blockIdx.x;
    const int i0   = blockIdx.y << 2;
    const int tid  = threadIdx.x;
    const int wave = tid >> 6;
    const int lane = tid & 63;

    const int tau = tau_arr[b];
    float* block_out = adj + ((size_t)b * NN + i0) * NN;

    if (i0 >= tau) {                          // whole block inactive: 32 KB zeros
        const f32x4 z = (f32x4){0.f, 0.f, 0.f, 0.f};
        f32x4* out4 = (f32x4*)block_out;
        #pragma unroll
        for (int t = 0; t < 8; ++t)
            __builtin_nontemporal_store(z, &out4[tid + (t << 8)]);
        return;
    }

    const int i = i0 + wave;
    f32x4* out4 = (f32x4*)(block_out + (size_t)wave * NN);

    if (i >= tau) {                           // inactive row in active block
        const f32x4 z = (f32x4){0.f, 0.f, 0.f, 0.f};
        #pragma unroll
        for (int t = 0; t < 8; ++t)
            __builtin_nontemporal_store(z, &out4[(t << 6) + lane]);
        return;
    }

    const int T = T_arr[b];
    const int M = T + tau;                    // src_valid: j < M (<= 2046)
    const float* base = PACKED ? xyz + (size_t)b * NN * 4
                               : xyz + (size_t)b * NN * FF;
    __shared__ unsigned swords[4][64];        // 1 KiB: per-wave column words

    const int g = T + i;                      // sink global index (< M always)
    const f32x4 sp = load_xyz<PACKED>(base, g);
    const float sxv = sp.x, syv = sp.y, szv = sp.z;

    // ---- one-pass build of per-lane sorted top-4 queue (L2 reads) ----
    unsigned long long q0 = INF_KEY, q1 = INF_KEY, q2 = INF_KEY, q3 = INF_KEY;
    const int S = (M + 63) >> 6;
    #pragma unroll 4
    for (int s = 0; s < S; ++s) {
        const int j = lane + (s << 6);
        if (j < M) {
            const f32x4 v = load_xyz<PACKED>(base, j);
            float dx = __fsub_rn(sxv, v.x);
            float dy = __fsub_rn(syv, v.y);
            float dz = __fsub_rn(szv, v.z);
            float d2 = __fadd_rn(__fadd_rn(__fmul_rn(dx, dx), __fmul_rn(dy, dy)),
                                 __fmul_rn(dz, dz));
            unsigned long long key =
                ((unsigned long long)__float_as_uint(d2) << 32) | (unsigned)(j + 1);
            if (key < q3) {
                q3 = key;
                unsigned long long t;
                if (q3 < q2) { t = q2; q2 = q3; q3 = t; }
                if (q2 < q1) { t = q1; q1 = q2; q2 = t; }
                if (q1 < q0) { t = q0; q0 = q1; q1 = t; }
            }
        }
    }

    // ---- 16 extraction rounds: DPP min on head d2 + ballot index resolve ----
    unsigned colmask = 0;                     // this lane's cols [32*lane, +32)
    unsigned long long lastpop = 0;
    for (int k = 0; k < KK; ++k) {
        const unsigned hd = (unsigned)(q0 >> 32);
        const unsigned m  = wave_min_u32(hd);
        if (m == 0xFFFFFFFFu) break;          // all lanes exhausted

        const unsigned long long mask = __ballot(hd == m);
        unsigned jwin;
        if (__popcll(mask) == 1) {            // unique head d2 (common case)
            const int w = __builtin_ctzll(mask);
            jwin = (unsigned)__builtin_amdgcn_readlane((int)(unsigned)q0, w);
        } else {                              // cross-lane d2 tie (rare)
            unsigned jc = (hd == m) ? (unsigned)q0 : 0xFFFFFFFFu;
            jwin = wave_min_u32(jc);
        }
        const int j = (int)jwin - 1;

        if (j < i && (j >> 5) == lane)        // causal + word ownership
            colmask |= 1u << (j & 31);

        if (hd == m && (unsigned)q0 == jwin) {  // pop on the winner lane
            lastpop = ((unsigned long long)m << 32) | jwin;
            q0 = q1; q1 = q2; q2 = q3; q3 = INF_KEY;
            if (q0 == INF_KEY) {              // rare: >4 global hits this lane
                unsigned long long best = INF_KEY;
                for (int s2 = 0; s2 < S; ++s2) {
                    const int jj = lane + (s2 << 6);
                    if (jj < M) {
                        const f32x4 v = load_xyz<PACKED>(base, jj);
                        float dx = __fsub_rn(sxv, v.x);
                        float dy = __fsub_rn(syv, v.y);
                        float dz = __fsub_rn(szv, v.z);
                        float d2 = __fadd_rn(
                            __fadd_rn(__fmul_rn(dx, dx), __fmul_rn(dy, dy)),
                            __fmul_rn(dz, dz));
                        unsigned long long kk =
                            ((unsigned long long)__float_as_uint(d2) << 32)
                            | (unsigned)(jj + 1);
                        if (kk > lastpop && kk < best) best = kk;
                    }
                }
                q0 = best;
            }
        }
    }

    // ---- route words through LDS (same wave: no barrier), stream the row ----
    swords[wave][lane] = colmask;
    #pragma unroll
    for (int k = 0; k < 8; ++k) {
        // cols c = 256k + 4*lane .. +3 ; word = 8k + (lane>>3) (broadcast read)
        const unsigned w   = swords[wave][(k << 3) + (lane >> 3)];
        const unsigned nib = (w >> ((lane & 7) << 2)) & 0xFu;
        f32x4 v;
        v.x = (nib & 1u) ? 1.0f : 0.0f;
        v.y = (nib & 2u) ? 1.0f : 0.0f;
        v.z = (nib & 4u) ? 1.0f : 0.0f;
        v.w = (nib & 8u) ? 1.0f : 0.0f;
        __builtin_nontemporal_store(v, &out4[(k << 6) + lane]);
    }
}

extern "C" void kernel_launch(void* const* d_in, const int* in_sizes, int n_in,
                              void* d_out, int out_size, void* d_ws, size_t ws_size,
                              hipStream_t stream) {
    const float* nodes = (const float*)d_in[0];
    const int*   T     = (const int*)d_in[1];
    const int*   taus  = (const int*)d_in[2];
    float*       adj   = (float*)d_out;
    const int B = in_sizes[1];               // T has B elements (16)

    dim3 grid(B, NN / 4);                    // 16 x 512 blocks, 256 thr each
    const size_t need = (size_t)B * NN * sizeof(f32x4);

    if (d_ws != nullptr && ws_size >= need) {
        const int total = B * NN;
        pack_xyz<<<dim3((total + 255) / 256), dim3(256), 0, stream>>>(
            nodes, (f32x4*)d_ws, total);
        knn_adj_fused<true><<<grid, dim3(256), 0, stream>>>(
            (const float*)d_ws, T, taus, adj);
    } else {
        knn_adj_fused<false><<<grid, dim3(256), 0, stream>>>(
            nodes, T, taus, adj);
    }
}